// Round 4
// baseline (294.141 us; speedup 1.0000x reference)
//
#include <hip/hip_runtime.h>
#include <hip/hip_bf16.h>

typedef __attribute__((ext_vector_type(8))) short short8;
typedef __attribute__((ext_vector_type(4))) float floatx4;
typedef __attribute__((ext_vector_type(8))) _Float16 half8;
typedef __attribute__((ext_vector_type(4))) _Float16 half4;

using bf16 = __hip_bfloat16;
using fp16 = _Float16;

#define S_LEN 2048
#define DM 1024
#define NH 16
#define DH 64
#define WIN 256

// ---------- helpers ----------
__device__ __forceinline__ unsigned short f2b(float f) {
  __hip_bfloat16 h = __float2bfloat16(f);
  return *reinterpret_cast<unsigned short*>(&h);
}
__device__ __forceinline__ unsigned short f2h(float f) {
  fp16 h = (fp16)f;
  return *reinterpret_cast<unsigned short*>(&h);
}
__device__ __forceinline__ void lds_load16(void* lds, const void* gptr) {
  __builtin_amdgcn_global_load_lds(
      (const __attribute__((address_space(1))) unsigned int*)gptr,
      (__attribute__((address_space(3))) unsigned int*)lds, 16, 0, 0);
}

// ---------- K1: x fp32 -> bf16 ----------
__global__ __launch_bounds__(256) void k_convert_x(const float4* __restrict__ in,
                                                   ushort4* __restrict__ out) {
  int i = blockIdx.x * 256 + threadIdx.x;
  float4 v = in[i];
  ushort4 r;
  r.x = f2b(v.x); r.y = f2b(v.y); r.z = f2b(v.z); r.w = f2b(v.w);
  out[i] = r;
}

// ---------- K2: W[k][n] fp32 -> Wt[n][k] bf16 (4 matrices) ----------
__global__ __launch_bounds__(256) void k_transpose_cvt(const float* __restrict__ W0,
                                                       const float* __restrict__ W1,
                                                       const float* __restrict__ W2,
                                                       const float* __restrict__ W3,
                                                       bf16* __restrict__ out) {
  __shared__ float t[32][33];
  const float* W = (blockIdx.z == 0) ? W0 : (blockIdx.z == 1) ? W1 : (blockIdx.z == 2) ? W2 : W3;
  bf16* O = out + (size_t)blockIdx.z * 1024 * 1024;
  int x0 = blockIdx.x * 32, y0 = blockIdx.y * 32;
  int tx = threadIdx.x, ty = threadIdx.y;  // block (32,8)
  #pragma unroll
  for (int i = 0; i < 32; i += 8) t[ty + i][tx] = W[(size_t)(y0 + ty + i) * 1024 + x0 + tx];
  __syncthreads();
  #pragma unroll
  for (int i = 0; i < 32; i += 8)
    O[(size_t)(x0 + ty + i) * 1024 + y0 + tx] = __float2bfloat16(t[tx][ty + i]);
}

// ---------- K3/K5: bf16 MFMA GEMM, C = A[M][1024] * Bt[N][1024]^T ----------
// MODE 0: N=3072 (Wq|Wk|Wv) -> Qh/Kh [bh][s][64] fp16; V transposed: Vt [bh][d][s] fp16
// MODE 1: N=1024 (Wo) -> fp32 [m][1024]
template <int MODE>
__global__ __launch_bounds__(256) void k_gemm(const bf16* __restrict__ A,
                                              const bf16* __restrict__ Bt,
                                              const float* __restrict__ bias_q,
                                              const float* __restrict__ bias_k,
                                              const float* __restrict__ bias_v,
                                              fp16* __restrict__ Qh, fp16* __restrict__ Kh,
                                              fp16* __restrict__ Vt, float* __restrict__ outF) {
  __shared__ __align__(16) bf16 As[128 * 32];
  __shared__ __align__(16) bf16 Bs[128 * 32];
  const int tid = threadIdx.x;
  const int wave = tid >> 6, lane = tid & 63;
  const int m0 = blockIdx.y * 128, n0 = blockIdx.x * 128;
  const int r0 = tid >> 2;
  const int cb = (tid & 3) * 16;
  const char* Ag = (const char*)A + (size_t)(m0 + r0) * 2048 + cb;
  const char* Bg = (const char*)Bt + (size_t)(n0 + r0) * 2048 + cb;
  char* AsW0 = (char*)As + wave * 1024;
  char* AsW1 = (char*)As + 4096 + wave * 1024;
  char* BsW0 = (char*)Bs + wave * 1024;
  char* BsW1 = (char*)Bs + 4096 + wave * 1024;
  const int wm = (wave & 1) * 64, wn = (wave >> 1) * 64;
  const int ln = lane & 15, quad = lane >> 4;

  floatx4 acc[4][4];
  #pragma unroll
  for (int i = 0; i < 4; i++)
    #pragma unroll
    for (int j = 0; j < 4; j++) acc[i][j] = (floatx4){0.f, 0.f, 0.f, 0.f};

  for (int k0 = 0; k0 < 1024; k0 += 32) {
    __syncthreads();
    lds_load16(AsW0, Ag + k0 * 2);
    lds_load16(AsW1, Ag + 64 * 2048 + k0 * 2);
    lds_load16(BsW0, Bg + k0 * 2);
    lds_load16(BsW1, Bg + 64 * 2048 + k0 * 2);
    __syncthreads();
    short8 af[4], bfr[4];
    #pragma unroll
    for (int mi = 0; mi < 4; mi++)
      af[mi] = *(const short8*)&As[(wm + mi * 16 + ln) * 32 + quad * 8];
    #pragma unroll
    for (int ni = 0; ni < 4; ni++)
      bfr[ni] = *(const short8*)&Bs[(wn + ni * 16 + ln) * 32 + quad * 8];
    #pragma unroll
    for (int mi = 0; mi < 4; mi++)
      #pragma unroll
      for (int ni = 0; ni < 4; ni++)
        acc[mi][ni] = __builtin_amdgcn_mfma_f32_16x16x32_bf16(af[mi], bfr[ni], acc[mi][ni], 0, 0, 0);
  }

  if constexpr (MODE == 0) {
    #pragma unroll
    for (int ni = 0; ni < 4; ni++) {
      int n = n0 + wn + ni * 16 + ln;  // 0..3071; g uniform across the wave
      int g = n >> 10, nn = n & 1023;
      int h = nn >> 6, dd = nn & 63;
      if (g == 2) {  // V -> Vt[bh][d][s] fp16, 4 consecutive s per 8B store
        float bias = bias_v[nn];
        #pragma unroll
        for (int mi = 0; mi < 4; mi++) {
          int m = m0 + wm + mi * 16 + quad * 4;
          int b = m >> 11, s = m & 2047;
          ushort4 pk;
          pk.x = f2h(acc[mi][ni][0] + bias);
          pk.y = f2h(acc[mi][ni][1] + bias);
          pk.z = f2h(acc[mi][ni][2] + bias);
          pk.w = f2h(acc[mi][ni][3] + bias);
          *(ushort4*)&Vt[((size_t)(b * NH + h) * DH + dd) * S_LEN + s] = pk;
        }
      } else {
        const float* bp = (g == 0) ? bias_q : bias_k;
        fp16* og = (g == 0) ? Qh : Kh;
        float bias = bp[nn];
        #pragma unroll
        for (int mi = 0; mi < 4; mi++) {
          #pragma unroll
          for (int r = 0; r < 4; r++) {
            int m = m0 + wm + mi * 16 + quad * 4 + r;
            int b = m >> 11, s = m & 2047;
            og[(size_t)((b * NH + h) * S_LEN + s) * DH + dd] = (fp16)(acc[mi][ni][r] + bias);
          }
        }
      }
    }
  } else {
    #pragma unroll
    for (int ni = 0; ni < 4; ni++) {
      int n = n0 + wn + ni * 16 + ln;
      float bias = bias_q[n];
      #pragma unroll
      for (int mi = 0; mi < 4; mi++)
        #pragma unroll
        for (int r = 0; r < 4; r++) {
          int m = m0 + wm + mi * 16 + quad * 4 + r;
          outF[(size_t)m * 1024 + n] = acc[mi][ni][r] + bias;
        }
    }
  }
}

// ---------- K4: register-resident MFMA flash attention (S^T trick) ----------
// S^T = K Q^T via 16x16x32_f16: C layout (col=q=ln, row=j=quad*4+r) == B-frag
// layout of 16x16x16f16 (n=ln, k=quad*4+i), so P goes accumulator->PV directly.
// No LDS, no barriers; waves fully independent. O accumulates transposed
// (col=q=ln, row=d_local=quad*4+r per 16-row d-tile).
__global__ __launch_bounds__(256, 4) void k_attn(const fp16* __restrict__ Qh,
                                                 const fp16* __restrict__ Kh,
                                                 const fp16* __restrict__ Vt,
                                                 bf16* __restrict__ aout) {
  const int tid = threadIdx.x;
  const int w = tid >> 6, lane = tid & 63;
  const int ln = lane & 15, quad = lane >> 4;
  const int bh = blockIdx.y;
  const int qw = blockIdx.x * 64 + w * 16;  // wave's first query
  const size_t base = (size_t)bh * S_LEN * DH;
  const fp16* Qp = Qh + base;
  const fp16* Kp = Kh + base;
  const fp16* Vp = Vt + base;  // [d][s]

  // Q as B-frag for 16x16x32: lane holds Q[q=qw+ln][d=quad*8+j (+32)]
  const half8 bq0 = *(const half8*)(Qp + (size_t)(qw + ln) * DH + quad * 8);
  const half8 bq1 = *(const half8*)(Qp + (size_t)(qw + ln) * DH + 32 + quad * 8);

  floatx4 acc[4];  // O^T tiles: dt -> d=dt*16+quad*4+r, col q=ln
  #pragma unroll
  for (int dt = 0; dt < 4; dt++) acc[dt] = (floatx4){0.f, 0.f, 0.f, 0.f};
  float m_i = -3.0e38f, l_i = 0.f;  // per-lane: q = qw + ln

  const float SC2 = 0.18033688011112042f;  // 0.125 * log2(e)

  auto process = [&](int c) {
    // ---- prefetch V^T A-frags (16x16x16): lane holds V^T[d=dt*16+ln][j=c+jt*16+quad*4+i]
    half4 vf[4][4];
    #pragma unroll
    for (int dt = 0; dt < 4; dt++)
      #pragma unroll
      for (int jt = 0; jt < 4; jt++)
        vf[dt][jt] = *(const half4*)(Vp + (size_t)(dt * 16 + ln) * S_LEN + c + jt * 16 + quad * 4);

    // ---- S^T = K Q^T (A=K rows, B=Q) ----
    floatx4 s[4];
    #pragma unroll
    for (int jt = 0; jt < 4; jt++) {
      const fp16* kr = Kp + (size_t)(c + jt * 16 + ln) * DH;
      half8 ak0 = *(const half8*)(kr + quad * 8);
      half8 ak1 = *(const half8*)(kr + 32 + quad * 8);
      floatx4 z = (floatx4){0.f, 0.f, 0.f, 0.f};
      z = __builtin_amdgcn_mfma_f32_16x16x32_f16(ak0, bq0, z, 0, 0, 0);
      s[jt] = __builtin_amdgcn_mfma_f32_16x16x32_f16(ak1, bq1, z, 0, 0, 0);
    }

    // ---- mask + scale into exp2 domain; s[jt][r]: j=c+jt*16+quad*4+r, q=qw+ln
    const bool full_in = (c >= qw - 241) && (c <= qw + 193);
    if (full_in) {
      #pragma unroll
      for (int jt = 0; jt < 4; jt++)
        #pragma unroll
        for (int r = 0; r < 4; r++) s[jt][r] *= SC2;
    } else {
      const int q = qw + ln;
      #pragma unroll
      for (int jt = 0; jt < 4; jt++) {
        #pragma unroll
        for (int r = 0; r < 4; r++) {
          int j = c + jt * 16 + quad * 4 + r;
          int d = q - j;
          bool ok = (d <= WIN && d >= -WIN) || (q == 0) || (j == 0);
          s[jt][r] = ok ? s[jt][r] * SC2 : -3.0e38f;
        }
      }
    }

    // ---- online softmax over j: per-lane fold (16 vals) + 2 shfl stages ----
    float mx = fmaxf(fmaxf(fmaxf(s[0][0], s[0][1]), fmaxf(s[0][2], s[0][3])),
                     fmaxf(fmaxf(s[1][0], s[1][1]), fmaxf(s[1][2], s[1][3])));
    mx = fmaxf(mx, fmaxf(fmaxf(fmaxf(s[2][0], s[2][1]), fmaxf(s[2][2], s[2][3])),
                         fmaxf(fmaxf(s[3][0], s[3][1]), fmaxf(s[3][2], s[3][3]))));
    mx = fmaxf(mx, __shfl_xor(mx, 16, 64));
    mx = fmaxf(mx, __shfl_xor(mx, 32, 64));
    float mnew = fmaxf(m_i, mx);
    float alpha = exp2f(m_i - mnew);
    m_i = mnew;

    half4 Pt[4];  // == B-frag of 16x16x16f16 directly
    float ss = 0.f;
    #pragma unroll
    for (int jt = 0; jt < 4; jt++) {
      #pragma unroll
      for (int r = 0; r < 4; r++) {
        float pe = exp2f(s[jt][r] - mnew);
        Pt[jt][r] = (fp16)pe;
        ss += pe;
      }
    }
    ss += __shfl_xor(ss, 16, 64);
    ss += __shfl_xor(ss, 32, 64);
    l_i = l_i * alpha + ss;

    #pragma unroll
    for (int dt = 0; dt < 4; dt++)
      #pragma unroll
      for (int r = 0; r < 4; r++) acc[dt][r] *= alpha;

    // ---- O^T += V^T P^T ----
    #pragma unroll
    for (int dt = 0; dt < 4; dt++)
      #pragma unroll
      for (int jt = 0; jt < 4; jt++)
        acc[dt] = __builtin_amdgcn_mfma_f32_16x16x16f16(vf[dt][jt], Pt[jt], acc[dt], 0, 0, 0);
  };

  // chunk 0 first (global col j=0 keeps every row's running max finite)
  process(0);
  int cs = qw - WIN; if (cs < 0) cs = 0; cs &= ~63;
  int ce = qw + 15 + WIN + 1; if (ce > S_LEN) ce = S_LEN; else ce = (ce + 63) & ~63;
  if (qw == 0) ce = S_LEN;
  for (int c = (cs < 64 ? 64 : cs); c < ce; c += 64) process(c);

  // ---- epilogue: normalize + write bf16 [b][q][h*64+d], 8B packed stores ----
  const int b = bh >> 4, h = bh & 15;
  const float inv = 1.0f / l_i;
  const int q = qw + ln;
  #pragma unroll
  for (int dt = 0; dt < 4; dt++) {
    ushort4 pk;
    pk.x = f2b(acc[dt][0] * inv);
    pk.y = f2b(acc[dt][1] * inv);
    pk.z = f2b(acc[dt][2] * inv);
    pk.w = f2b(acc[dt][3] * inv);
    *(ushort4*)&aout[(size_t)(b * S_LEN + q) * DM + h * DH + dt * 16 + quad * 4] = pk;
  }
}

// ---------- launch ----------
extern "C" void kernel_launch(void* const* d_in, const int* in_sizes, int n_in,
                              void* d_out, int out_size, void* d_ws, size_t ws_size,
                              hipStream_t stream) {
  const float* x  = (const float*)d_in[0];
  const float* Wq = (const float*)d_in[1];
  const float* bq = (const float*)d_in[2];
  const float* Wk = (const float*)d_in[3];
  const float* bk = (const float*)d_in[4];
  const float* Wv = (const float*)d_in[5];
  const float* bv = (const float*)d_in[6];
  const float* Wo = (const float*)d_in[7];
  const float* bo = (const float*)d_in[8];
  float* out = (float*)d_out;

  const size_t SEG = (size_t)4096 * 1024;
  bf16* xb = (bf16*)d_ws;
  bf16* wT = xb + SEG;
  fp16* Qh = (fp16*)(wT + SEG);
  fp16* Kh = Qh + SEG;
  fp16* Vt = Kh + SEG;   // [bh][d][s]
  bf16* ao = (bf16*)(Vt + SEG);

  k_convert_x<<<dim3(4096), dim3(256), 0, stream>>>((const float4*)x, (ushort4*)xb);
  k_transpose_cvt<<<dim3(32, 32, 4), dim3(32, 8), 0, stream>>>(Wq, Wk, Wv, Wo, wT);
  k_gemm<0><<<dim3(24, 32), dim3(256), 0, stream>>>(xb, wT, bq, bk, bv, Qh, Kh, Vt, nullptr);
  k_attn<<<dim3(32, 32), dim3(256), 0, stream>>>(Qh, Kh, Vt, ao);
  k_gemm<1><<<dim3(8, 32), dim3(256), 0, stream>>>(ao, wT + (size_t)3 * 1024 * 1024, bo,
                                                   nullptr, nullptr, nullptr, nullptr, nullptr, out);
}